// Round 2
// baseline (28065.970 us; speedup 1.0000x reference)
//
#include <hip/hip_runtime.h>
#include <hip/hip_fp16.h>

#define L_SEQ 2048
#define N_B   64
#define IN_K  128
#define MEM_N 256

typedef float    f32x4 __attribute__((ext_vector_type(4)));
typedef _Float16 f16x8 __attribute__((ext_vector_type(8)));
typedef _Float16 f16x4 __attribute__((ext_vector_type(4)));

__device__ __forceinline__ float rcp_f(float x) { return __builtin_amdgcn_rcpf(x); }
__device__ __forceinline__ float tanh_f(float x) {
    // robust: x->+inf => exp=inf => 1-0 = 1 ; x->-inf => exp=0 => 1-2 = -1
    return 1.0f - 2.0f * rcp_f(__expf(2.0f * x) + 1.0f);
}
__device__ __forceinline__ float sig_f(float x) {
    return rcp_f(1.0f + __expf(-x));
}

// split-f16: v ~= hi + lo with ~22-bit effective mantissa
__device__ __forceinline__ void split8(const float* v, f16x8& hi, f16x8& lo) {
#pragma unroll
    for (int i = 0; i < 8; ++i) {
        _Float16 h = (_Float16)v[i];
        hi[i] = h;
        lo[i] = (_Float16)(v[i] - (float)h);
    }
}

// 64 WGs: group g = wg&3 (members stride-4 -> ~2 XCDs/group under round-robin
// dispatch) owns batches [16g,16g+16); slice s = wg>>2 owns rows [16s,16s+16).
// Weights live in VGPRs as split-f16 (loaded once). Per step: input-proj MFMAs
// (pre-spin), spin on group flags, hidden MFMAs from split-f16 published hf,
// LDS cross-wave reduce, f32 pointwise, publish hfn (hi+lo f16) + release flag.
__global__ void __launch_bounds__(256, 1)
befrc_scan(const float* __restrict__ u,
           const float* __restrict__ Wia, const float* __restrict__ Wha,
           const float* __restrict__ Wib, const float* __restrict__ Whb,
           const float* __restrict__ Wic, const float* __restrict__ Whc,
           const float* __restrict__ Wid, const float* __restrict__ Whd,
           const float* __restrict__ Wie, const float* __restrict__ Whe,
           const float* __restrict__ Wio,
           float* __restrict__ out,           // [64][2048][256] f32 then [64][256] f32
           _Float16* __restrict__ pub_hi,     // [2][64][256] f16 (zeroed before launch)
           _Float16* __restrict__ pub_lo,     // [2][64][256] f16 (zeroed before launch)
           unsigned int* __restrict__ flags)  // [64] u32 (zeroed before launch)
{
    const int wg  = blockIdx.x;       // 0..63
    const int g   = wg & 3;           // group 0..3 (stride-4 members)
    const int s   = wg >> 2;          // m-slice 0..15
    const int tid = threadIdx.x;      // 0..255
    const int w   = tid >> 6;         // wave 0..3
    const int l   = tid & 63;
    const int lq  = l >> 4;           // 0..3
    const int lr  = l & 15;           // 0..15

    __shared__ __align__(16) float red[6][4][16][16]; // [gate][wave][b(col)][m(row)] 24KB

    const float* Wi[6] = {Wia, Wib, Wic, Wid, Wie, Wio};
    const float* Wh[5] = {Wha, Whb, Whc, Whd, Whe};

    // ---- preload weight fragments into registers, split-f16 (step-invariant) ----
    // A-frag slot (q=lane>>4, j): logical k = chunk*32 + q*4 + (j&3) + 16*(j>>2).
    // Any bijective k-slot guess is safe as long as A and B use the same one.
    const int mrow = s * 16 + lr;
    f16x8 whf_hi[5][2], whf_lo[5][2];
#pragma unroll
    for (int gg = 0; gg < 5; ++gg) {
#pragma unroll
        for (int cc = 0; cc < 2; ++cc) {
            const int k0 = (2 * w + cc) * 32 + lq * 4;
            const float* p = Wh[gg] + mrow * MEM_N + k0;
            float4 f0 = *(const float4*)p;
            float4 f1 = *(const float4*)(p + 16);
            float v[8] = {f0.x, f0.y, f0.z, f0.w, f1.x, f1.y, f1.z, f1.w};
            split8(v, whf_hi[gg][cc], whf_lo[gg][cc]);
        }
    }
    f16x8 wif_hi[6], wif_lo[6];
#pragma unroll
    for (int gg = 0; gg < 6; ++gg) {
        const int k0 = w * 32 + lq * 4;
        const float* p = Wi[gg] + mrow * IN_K + k0;
        float4 f0 = *(const float4*)p;
        float4 f1 = *(const float4*)(p + 16);
        float v[8] = {f0.x, f0.y, f0.z, f0.w, f1.x, f1.y, f1.z, f1.w};
        split8(v, wif_hi[gg], wif_lo[gg]);
    }

    // element mapping for the pointwise phase: one element per thread
    const int eb    = tid >> 4;          // batch col 0..15
    const int em    = tid & 15;          // m row local 0..15
    const int bglob = g * 16 + eb;
    const int mglob = s * 16 + em;
    float hf_loc = 0.0f, hs_loc = 0.0f;

    const int  bfrag  = g * 16 + lr;                 // batch for B-operand col = lane&15
    const long u_base = (long)bfrag * L_SEQ * IN_K;  // u[b][t][k]
    const int  fbase  = g * 16;

    for (int t = 0; t < L_SEQ; ++t) {
        // ---- A: input projections (independent of hf -> before the spin) ----
        f32x4 acc[6];
#pragma unroll
        for (int gg = 0; gg < 6; ++gg) acc[gg] = (f32x4){0.f, 0.f, 0.f, 0.f};
        {
            const float* up = u + u_base + (long)t * IN_K + w * 32 + lq * 4;
            float4 f0 = *(const float4*)up;
            float4 f1 = *(const float4*)(up + 16);
            float v[8] = {f0.x, f0.y, f0.z, f0.w, f1.x, f1.y, f1.z, f1.w};
            f16x8 ub_hi, ub_lo;
            split8(v, ub_hi, ub_lo);
#pragma unroll
            for (int gg = 0; gg < 6; ++gg) {
                acc[gg] = __builtin_amdgcn_mfma_f32_16x16x32_f16(wif_hi[gg], ub_hi, acc[gg], 0, 0, 0);
                acc[gg] = __builtin_amdgcn_mfma_f32_16x16x32_f16(wif_hi[gg], ub_lo, acc[gg], 0, 0, 0);
                acc[gg] = __builtin_amdgcn_mfma_f32_16x16x32_f16(wif_lo[gg], ub_hi, acc[gg], 0, 0, 0);
            }
        }

        // ---- B: wait until all 16 WGs of the group published step t ----
        if (t > 0) {
            const unsigned tgt = (unsigned)t;
            int spins = 0;
            for (;;) {
                unsigned v = __hip_atomic_load(&flags[fbase + (l & 15)],
                                               __ATOMIC_RELAXED, __HIP_MEMORY_SCOPE_AGENT);
                if (__all((int)(v >= tgt)) || ++spins > (1 << 22)) break;
                __builtin_amdgcn_s_sleep(1);
            }
            __threadfence();   // acquire: invalidate so pub loads see fresh data
        }

        // ---- C: hidden matvecs from published hf (split-f16) ----
        {
            const size_t pbase = (size_t)(t & 1) * N_B * MEM_N + (size_t)bfrag * MEM_N;
#pragma unroll
            for (int cc = 0; cc < 2; ++cc) {
                const int k0 = (2 * w + cc) * 32 + lq * 4;
                f16x4 a0 = *(const f16x4*)(pub_hi + pbase + k0);
                f16x4 a1 = *(const f16x4*)(pub_hi + pbase + k0 + 16);
                f16x4 b0 = *(const f16x4*)(pub_lo + pbase + k0);
                f16x4 b1 = *(const f16x4*)(pub_lo + pbase + k0 + 16);
                f16x8 hb_hi, hb_lo;
                hb_hi[0] = a0[0]; hb_hi[1] = a0[1]; hb_hi[2] = a0[2]; hb_hi[3] = a0[3];
                hb_hi[4] = a1[0]; hb_hi[5] = a1[1]; hb_hi[6] = a1[2]; hb_hi[7] = a1[3];
                hb_lo[0] = b0[0]; hb_lo[1] = b0[1]; hb_lo[2] = b0[2]; hb_lo[3] = b0[3];
                hb_lo[4] = b1[0]; hb_lo[5] = b1[1]; hb_lo[6] = b1[2]; hb_lo[7] = b1[3];
#pragma unroll
                for (int gg = 0; gg < 5; ++gg) {
                    acc[gg] = __builtin_amdgcn_mfma_f32_16x16x32_f16(whf_hi[gg][cc], hb_hi, acc[gg], 0, 0, 0);
                    acc[gg] = __builtin_amdgcn_mfma_f32_16x16x32_f16(whf_hi[gg][cc], hb_lo, acc[gg], 0, 0, 0);
                    acc[gg] = __builtin_amdgcn_mfma_f32_16x16x32_f16(whf_lo[gg][cc], hb_hi, acc[gg], 0, 0, 0);
                }
            }
        }

        // ---- D: cross-wave partial exchange (writer-contiguous b128, 2-way banks) ----
#pragma unroll
        for (int gg = 0; gg < 6; ++gg)
            *(f32x4*)&red[gg][w][lr][lq * 4] = acc[gg];
        __syncthreads();

        // ---- E: reduce + pointwise update (f32 masters stay in registers) ----
        float pre[6];
#pragma unroll
        for (int gg = 0; gg < 6; ++gg)
            pre[gg] = red[gg][0][eb][em] + red[gg][1][eb][em]
                    + red[gg][2][eb][em] + red[gg][3][eb][em];
        {
            const float av  = 1.0f + tanh_f(pre[0]);
            const float bv  = 1.5f * (1.0f + tanh_f(pre[1]));
            const float cv  = 0.3f  + 0.7f * sig_f(pre[2]);   // 3*DT + (1-3*DT)*sig
            const float dv  = 0.03f * sig_f(pre[3]);          // 0.3*DT*sig
            const float ev  = 1.0f + sig_f(pre[4]);
            const float arg = pre[5] + (av + bv * hf_loc * hf_loc - hs_loc) * hf_loc;
            const float hfn = (1.0f - cv) * hf_loc + cv * tanh_f(arg);
            const float eh  = ev * hf_loc;
            const float eh2 = eh * eh;
            const float hsn = hs_loc * (1.0f - dv) + dv * (eh2 * eh2);
            hf_loc = hfn; hs_loc = hsn;
        }
        // publish hfn (split-f16) for next step's matvecs
        {
            const size_t po = (size_t)((t + 1) & 1) * N_B * MEM_N + (size_t)bglob * MEM_N + mglob;
            _Float16 ph = (_Float16)hf_loc;
            pub_hi[po] = ph;
            pub_lo[po] = (_Float16)(hf_loc - (float)ph);
        }

        // ---- F: release this WG's step ----
        __threadfence();      // make pub stores agent-visible
        __syncthreads();      // all 4 waves' stores fenced before the flag
        if (tid == 0)
            __hip_atomic_store(&flags[wg], (unsigned)(t + 1),
                               __ATOMIC_RELEASE, __HIP_MEMORY_SCOPE_AGENT);

        // ---- G: sequence output (off the critical inter-WG path) ----
        out[((long)bglob * L_SEQ + t) * MEM_N + mglob] = hf_loc;
        if (t == L_SEQ - 1)
            out[(long)N_B * L_SEQ * MEM_N + (long)bglob * MEM_N + mglob] = hf_loc;
    }
}

extern "C" void kernel_launch(void* const* d_in, const int* in_sizes, int n_in,
                              void* d_out, int out_size, void* d_ws, size_t ws_size,
                              hipStream_t stream) {
    (void)in_sizes; (void)n_in; (void)out_size; (void)ws_size;
    const float* u   = (const float*)d_in[0];
    const float* Wia = (const float*)d_in[1];
    const float* Wha = (const float*)d_in[2];
    const float* Wib = (const float*)d_in[3];
    const float* Whb = (const float*)d_in[4];
    const float* Wic = (const float*)d_in[5];
    const float* Whc = (const float*)d_in[6];
    const float* Wid = (const float*)d_in[7];
    const float* Whd = (const float*)d_in[8];
    const float* Wie = (const float*)d_in[9];
    const float* Whe = (const float*)d_in[10];
    const float* Wio = (const float*)d_in[11];

    float* out = (float*)d_out;
    const size_t PUB_BYTES = (size_t)2 * N_B * MEM_N * sizeof(_Float16); // 65536
    _Float16* pub_hi = (_Float16*)d_ws;
    _Float16* pub_lo = (_Float16*)((char*)d_ws + PUB_BYTES);
    unsigned int* flags = (unsigned int*)((char*)d_ws + 2 * PUB_BYTES);  // +256B

    // zero exchange buffers + flags (hf0 = 0, flags start at 0) — every launch,
    // deterministic, graph-capture safe
    hipMemsetAsync(d_ws, 0, 2 * PUB_BYTES + N_B * sizeof(unsigned int), stream);

    befrc_scan<<<dim3(64), dim3(256), 0, stream>>>(
        u, Wia, Wha, Wib, Whb, Wic, Whc, Wid, Whd, Wie, Whe, Wio,
        out, pub_hi, pub_lo, flags);
}

// Round 3
// 6666.957 us; speedup vs baseline: 4.2097x; 4.2097x over previous
//
#include <hip/hip_runtime.h>
#include <hip/hip_fp16.h>

#define L_SEQ 2048
#define N_B   64
#define IN_K  128
#define MEM_N 256

typedef float    f32x4 __attribute__((ext_vector_type(4)));
typedef _Float16 f16x8 __attribute__((ext_vector_type(8)));

__device__ __forceinline__ float rcp_f(float x) { return __builtin_amdgcn_rcpf(x); }
__device__ __forceinline__ float tanh_f(float x) {
    return 1.0f - 2.0f * rcp_f(__expf(2.0f * x) + 1.0f);
}
__device__ __forceinline__ float sig_f(float x) {
    return rcp_f(1.0f + __expf(-x));
}

// split-f16: v ~= hi + lo with ~22-bit effective mantissa
__device__ __forceinline__ void split8(const float* v, f16x8& hi, f16x8& lo) {
#pragma unroll
    for (int i = 0; i < 8; ++i) {
        _Float16 h = (_Float16)v[i];
        hi[i] = h;
        lo[i] = (_Float16)(v[i] - (float)h);
    }
}

// 64 WGs: group g = wg&3 owns batches [16g,16g+16); slice s = wg>>2 owns rows
// [16s,16s+16). Weights live in registers as split-f16 (loaded once).
// Inter-WG exchange: self-validating u64 slots {tag=t+1, payload=hf hi/lo f16}
// via RELAXED agent-scope atomics (sc0 sc1 accesses -> Infinity Cache).
// No fences, no flags, no L2 maintenance on the critical path.
__global__ void __launch_bounds__(256, 1)
befrc_scan(const float* __restrict__ u,
           const float* __restrict__ Wia, const float* __restrict__ Wha,
           const float* __restrict__ Wib, const float* __restrict__ Whb,
           const float* __restrict__ Wic, const float* __restrict__ Whc,
           const float* __restrict__ Wid, const float* __restrict__ Whd,
           const float* __restrict__ Wie, const float* __restrict__ Whe,
           const float* __restrict__ Wio,
           float* __restrict__ out,                    // [64][2048][256] f32 then [64][256] f32
           unsigned long long* __restrict__ pubq)      // [2][64][256] u64 (zeroed pre-launch)
{
    const int wg  = blockIdx.x;       // 0..63
    const int g   = wg & 3;           // group 0..3
    const int s   = wg >> 2;          // m-slice 0..15
    const int tid = threadIdx.x;      // 0..255
    const int w   = tid >> 6;         // wave 0..3
    const int l   = tid & 63;
    const int lq  = l >> 4;           // 0..3
    const int lr  = l & 15;           // 0..15

    __shared__ __align__(16) float red[2][6][4][16][16]; // double-buffered, 48KB

    const float* Wi[6] = {Wia, Wib, Wic, Wid, Wie, Wio};
    const float* Wh[5] = {Wha, Whb, Whc, Whd, Whe};

    // ---- preload weight fragments into registers, split-f16 (step-invariant) ----
    // A-frag slot (q=lane>>4, j): logical k = chunk*32 + q*4 + (j&3) + 16*(j>>2).
    // Bijective k-slot mapping used identically for A and B operands.
    const int mrow = s * 16 + lr;
    f16x8 whf_hi[5][2], whf_lo[5][2];
#pragma unroll
    for (int gg = 0; gg < 5; ++gg) {
#pragma unroll
        for (int cc = 0; cc < 2; ++cc) {
            const int k0 = (2 * w + cc) * 32 + lq * 4;
            const float* p = Wh[gg] + mrow * MEM_N + k0;
            float4 f0 = *(const float4*)p;
            float4 f1 = *(const float4*)(p + 16);
            float v[8] = {f0.x, f0.y, f0.z, f0.w, f1.x, f1.y, f1.z, f1.w};
            split8(v, whf_hi[gg][cc], whf_lo[gg][cc]);
        }
    }
    f16x8 wif_hi[6], wif_lo[6];
#pragma unroll
    for (int gg = 0; gg < 6; ++gg) {
        const int k0 = w * 32 + lq * 4;
        const float* p = Wi[gg] + mrow * IN_K + k0;
        float4 f0 = *(const float4*)p;
        float4 f1 = *(const float4*)(p + 16);
        float v[8] = {f0.x, f0.y, f0.z, f0.w, f1.x, f1.y, f1.z, f1.w};
        split8(v, wif_hi[gg], wif_lo[gg]);
    }

    // pointwise-phase element mapping: one element per thread
    const int eb    = tid >> 4;          // batch col 0..15
    const int em    = tid & 15;          // m row local 0..15
    const int bglob = g * 16 + eb;
    const int mglob = s * 16 + em;
    float hf_loc = 0.0f, hs_loc = 0.0f;

    const int  bfrag  = g * 16 + lr;                 // B-operand col = lane&15
    const long u_base = (long)bfrag * L_SEQ * IN_K;  // u[b][t][k]
    const int  k0a    = (2 * w + 0) * 32 + lq * 4;
    const int  k0b    = (2 * w + 1) * 32 + lq * 4;

    for (int t = 0; t < L_SEQ; ++t) {
        // ---- A: input projections (independent of hf -> issued before the spin) ----
        f32x4 acc[6];
#pragma unroll
        for (int gg = 0; gg < 6; ++gg) acc[gg] = (f32x4){0.f, 0.f, 0.f, 0.f};
        {
            const float* up = u + u_base + (long)t * IN_K + w * 32 + lq * 4;
            float4 f0 = *(const float4*)up;
            float4 f1 = *(const float4*)(up + 16);
            float v[8] = {f0.x, f0.y, f0.z, f0.w, f1.x, f1.y, f1.z, f1.w};
            f16x8 ub_hi, ub_lo;
            split8(v, ub_hi, ub_lo);
#pragma unroll
            for (int gg = 0; gg < 6; ++gg) {
                acc[gg] = __builtin_amdgcn_mfma_f32_16x16x32_f16(wif_hi[gg], ub_hi, acc[gg], 0, 0, 0);
                acc[gg] = __builtin_amdgcn_mfma_f32_16x16x32_f16(wif_hi[gg], ub_lo, acc[gg], 0, 0, 0);
                acc[gg] = __builtin_amdgcn_mfma_f32_16x16x32_f16(wif_lo[gg], ub_hi, acc[gg], 0, 0, 0);
            }
        }

        // ---- C: per-wave spin on the 16 self-validating slots this wave consumes ----
        unsigned long long q[16];
        {
            const unsigned tgt = (unsigned)t;
            const unsigned long long* pb =
                pubq + (size_t)(t & 1) * N_B * MEM_N + (size_t)bfrag * MEM_N;
            int spins = 0;
            for (;;) {
#pragma unroll
                for (int i = 0; i < 4; ++i) {
                    q[i]      = __hip_atomic_load(pb + k0a + i,      __ATOMIC_RELAXED, __HIP_MEMORY_SCOPE_AGENT);
                    q[4 + i]  = __hip_atomic_load(pb + k0a + 16 + i, __ATOMIC_RELAXED, __HIP_MEMORY_SCOPE_AGENT);
                    q[8 + i]  = __hip_atomic_load(pb + k0b + i,      __ATOMIC_RELAXED, __HIP_MEMORY_SCOPE_AGENT);
                    q[12 + i] = __hip_atomic_load(pb + k0b + 16 + i, __ATOMIC_RELAXED, __HIP_MEMORY_SCOPE_AGENT);
                }
                int ok = 1;
#pragma unroll
                for (int i = 0; i < 16; ++i)
                    ok &= ((unsigned)(q[i] >> 32) == tgt);
                if (__all(ok) || ++spins > (1 << 18)) break;
                __builtin_amdgcn_s_sleep(1);
            }
        }
        // unpack payloads + hidden matvecs
#pragma unroll
        for (int cc = 0; cc < 2; ++cc) {
            f16x8 hb_hi, hb_lo;
#pragma unroll
            for (int j = 0; j < 8; ++j) {
                const unsigned pay = (unsigned)q[cc * 8 + j];
                hb_hi[j] = __builtin_bit_cast(_Float16, (unsigned short)(pay & 0xffff));
                hb_lo[j] = __builtin_bit_cast(_Float16, (unsigned short)(pay >> 16));
            }
#pragma unroll
            for (int gg = 0; gg < 5; ++gg) {
                acc[gg] = __builtin_amdgcn_mfma_f32_16x16x32_f16(whf_hi[gg][cc], hb_hi, acc[gg], 0, 0, 0);
                acc[gg] = __builtin_amdgcn_mfma_f32_16x16x32_f16(whf_hi[gg][cc], hb_lo, acc[gg], 0, 0, 0);
                acc[gg] = __builtin_amdgcn_mfma_f32_16x16x32_f16(whf_lo[gg][cc], hb_hi, acc[gg], 0, 0, 0);
            }
        }

        // ---- D: cross-wave partial exchange (double-buffered -> single barrier) ----
        const int pb2 = t & 1;
#pragma unroll
        for (int gg = 0; gg < 6; ++gg)
            *(f32x4*)&red[pb2][gg][w][lr][lq * 4] = acc[gg];
        __syncthreads();

        // ---- E: reduce + pointwise update (f32 masters stay in registers) ----
        float pre[6];
#pragma unroll
        for (int gg = 0; gg < 6; ++gg)
            pre[gg] = red[pb2][gg][0][eb][em] + red[pb2][gg][1][eb][em]
                    + red[pb2][gg][2][eb][em] + red[pb2][gg][3][eb][em];
        {
            const float av  = 1.0f + tanh_f(pre[0]);
            const float bv  = 1.5f * (1.0f + tanh_f(pre[1]));
            const float cv  = 0.3f  + 0.7f * sig_f(pre[2]);   // 3*DT + (1-3*DT)*sig
            const float dv  = 0.03f * sig_f(pre[3]);          // 0.3*DT*sig
            const float ev  = 1.0f + sig_f(pre[4]);
            const float arg = pre[5] + (av + bv * hf_loc * hf_loc - hs_loc) * hf_loc;
            const float hfn = (1.0f - cv) * hf_loc + cv * tanh_f(arg);
            const float eh  = ev * hf_loc;
            const float eh2 = eh * eh;
            const float hsn = hs_loc * (1.0f - dv) + dv * (eh2 * eh2);
            hf_loc = hfn; hs_loc = hsn;
        }

        // ---- F: publish {tag, payload} as one relaxed agent-scope u64 ----
        {
            const _Float16 ph = (_Float16)hf_loc;
            const _Float16 pl = (_Float16)(hf_loc - (float)ph);
            const unsigned pay = (unsigned)__builtin_bit_cast(unsigned short, ph)
                               | ((unsigned)__builtin_bit_cast(unsigned short, pl) << 16);
            const unsigned long long val = ((unsigned long long)(unsigned)(t + 1) << 32) | pay;
            const size_t po = (size_t)((t + 1) & 1) * N_B * MEM_N
                            + (size_t)bglob * MEM_N + mglob;
            __hip_atomic_store(pubq + po, val, __ATOMIC_RELAXED, __HIP_MEMORY_SCOPE_AGENT);
        }

        // ---- G: sequence output (off the critical inter-WG path) ----
        out[((long)bglob * L_SEQ + t) * MEM_N + mglob] = hf_loc;
        if (t == L_SEQ - 1)
            out[(long)N_B * L_SEQ * MEM_N + (long)bglob * MEM_N + mglob] = hf_loc;
    }
}

extern "C" void kernel_launch(void* const* d_in, const int* in_sizes, int n_in,
                              void* d_out, int out_size, void* d_ws, size_t ws_size,
                              hipStream_t stream) {
    (void)in_sizes; (void)n_in; (void)out_size; (void)ws_size;
    const float* u   = (const float*)d_in[0];
    const float* Wia = (const float*)d_in[1];
    const float* Wha = (const float*)d_in[2];
    const float* Wib = (const float*)d_in[3];
    const float* Whb = (const float*)d_in[4];
    const float* Wic = (const float*)d_in[5];
    const float* Whc = (const float*)d_in[6];
    const float* Wid = (const float*)d_in[7];
    const float* Whd = (const float*)d_in[8];
    const float* Wie = (const float*)d_in[9];
    const float* Whe = (const float*)d_in[10];
    const float* Wio = (const float*)d_in[11];

    float* out = (float*)d_out;
    unsigned long long* pubq = (unsigned long long*)d_ws; // 2*64*256*8 = 262144 B

    // zero slot tags (tag 0 == step-0 expectation, payload 0 == hf0) — every
    // launch, deterministic, graph-capture safe
    hipMemsetAsync(d_ws, 0, (size_t)2 * N_B * MEM_N * sizeof(unsigned long long), stream);

    befrc_scan<<<dim3(64), dim3(256), 0, stream>>>(
        u, Wia, Wha, Wib, Whb, Wic, Whc, Wid, Whd, Wie, Whe, Wio,
        out, pubq);
}